// Round 17
// baseline (182.373 us; speedup 1.0000x reference)
//
#include <hip/hip_runtime.h>
#include <hip/hip_bf16.h>
#include <stdint.h>

typedef __bf16 bf16x8 __attribute__((ext_vector_type(8)));
typedef __bf16 bf16x4 __attribute__((ext_vector_type(4)));
typedef float  f32x4  __attribute__((ext_vector_type(4)));
typedef unsigned int u32x4 __attribute__((ext_vector_type(4)));

#define D_MODEL 1024
#define NUM_HEADS 16
#define D_K 64
#define BATCH 2
#define SEQ 2048
#define M_TOTAL (BATCH * SEQ)   // 4096

// 0.125 (1/sqrt(64)) * log2(e): folded into Q at the qkv epilogue so the
// attention softmax is a bare exp2 (v_exp_f32), no per-element scale mul.
#define Q_SCALE 0.18033688011112042f

static __device__ __forceinline__ bf16x8 load8(const __bf16* p) {
    return *reinterpret_cast<const bf16x8*>(p);
}

#define MFMA16(a, b, c) __builtin_amdgcn_mfma_f32_16x16x32_bf16((a), (b), (c), 0, 0, 0)

// Async global->LDS, 16B per lane. LDS dest = wave-uniform base + lane*16.
static __device__ __forceinline__ void gload16(const void* g, const void* lds) {
    __builtin_amdgcn_global_load_lds(
        (const __attribute__((address_space(1))) uint32_t*)g,
        (__attribute__((address_space(3))) uint32_t*)lds,
        16, 0, 0);
}

// Pack two f32 -> one u32 of 2 bf16 (lo = first arg). No builtin on gfx950.
static __device__ __forceinline__ uint32_t cvtpk(float lo, float hi) {
    uint32_t r;
    asm("v_cvt_pk_bf16_f32 %0, %1, %2" : "=v"(r) : "v"(lo), "v"(hi));
    return r;
}
// CDNA4 zip semantics ("DST rows 2:3 <-> SRC rows 0:1", rows = 16 lanes):
//   swap32: a' = (a@q0, a@q1, b@q0, b@q1), b' = (a@q2, a@q3, b@q2, b@q3)
static __device__ __forceinline__ void swap32(uint32_t& a, uint32_t& b) {
    asm("v_permlane32_swap_b32 %0, %1" : "+v"(a), "+v"(b));
}
// swap16 ("DST odd rows <-> SRC even rows"):
//   a' = (a@q0, b@q0, a@q2, b@q2), b' = (a@q1, b@q1, a@q3, b@q3)
static __device__ __forceinline__ void swap16(uint32_t& a, uint32_t& b) {
    asm("v_permlane16_swap_b32 %0, %1" : "+v"(a), "+v"(b));
}

// ---------------------------------------------------------------------------
// One launch: x (2048 blocks) + 4 weight matrices (512 blocks each) fp32->bf16.
// ---------------------------------------------------------------------------
__global__ __launch_bounds__(256) void convert_all(
    const float* __restrict__ X,
    const float* __restrict__ Wq, const float* __restrict__ Wk,
    const float* __restrict__ Wv, const float* __restrict__ Wo,
    __bf16* __restrict__ xb,
    __bf16* __restrict__ dq, __bf16* __restrict__ dk,
    __bf16* __restrict__ dv, __bf16* __restrict__ dw)
{
    const float* src; __bf16* dst; size_t idx;
    if (blockIdx.x < 2048) {
        src = X; dst = xb;
        idx = (size_t)blockIdx.x * 256 + threadIdx.x;
    } else {
        const int wb  = blockIdx.x - 2048;
        const int sel = wb >> 9;
        src = (sel == 0) ? Wq : (sel == 1) ? Wk : (sel == 2) ? Wv : Wo;
        dst = (sel == 0) ? dq : (sel == 1) ? dk : (sel == 2) ? dv : dw;
        idx = (size_t)(wb & 511) * 256 + threadIdx.x;
    }
    const f32x4 a = *reinterpret_cast<const f32x4*>(src + idx * 8);
    const f32x4 b = *reinterpret_cast<const f32x4*>(src + idx * 8 + 4);
    bf16x8 r;
#pragma unroll
    for (int e = 0; e < 4; e++) { r[e] = (__bf16)a[e]; r[4 + e] = (__bf16)b[e]; }
    *reinterpret_cast<bf16x8*>(dst + idx * 8) = r;
}

// ---------------------------------------------------------------------------
// QKV GEMM (R16 config): 128x128 tile, BK=64, swizzled gload16 staging,
// double-buffered prefetch loop (one barrier per K-step, next tile's loads
// in flight through compute). LDS 64 KB -> 2 blocks/CU. Q output pre-scaled
// by Q_SCALE. V transposed through LDS -> V^T. grid = (32, 24), block = 256.
// ---------------------------------------------------------------------------
__global__ __launch_bounds__(256) void qkv_kernel(
    const __bf16* __restrict__ Xb,
    const __bf16* __restrict__ Wqb,
    const __bf16* __restrict__ Wkb,
    const __bf16* __restrict__ Wvb,
    __bf16* __restrict__ Qb,
    __bf16* __restrict__ Kb,
    __bf16* __restrict__ Vtg)
{
    __shared__ alignas(16) char smem[65536];   // A[2]16K + B[2]16K; V scratch 34K
    __bf16* As0 = (__bf16*)smem;               // [2][128*64], chunk-swizzled
    __bf16* Bs0 = As0 + 2 * 128 * 64;

    const int lane = threadIdx.x & 63;
    const int wid  = threadIdx.x >> 6;
    const int m    = lane & 15;
    const int quad = lane >> 4;
    const int wrow = wid >> 1, wcol = wid & 1;
    const int row0 = blockIdx.x * 128;
    const int col0 = blockIdx.y * 128;
    const int wsel = col0 >> 10;
    const int lcol0 = col0 & 1023;

    const __bf16* W = (wsel == 0) ? Wqb : (wsel == 1) ? Wkb : Wvb;

    // staging: 128x64 A-tile + 128x64 B-tile into buffer `buf`
    auto stage = [&](int k0, int buf) {
#pragma unroll
        for (int i = 0; i < 4; i++) {
            const int slot = wid * 256 + i * 64 + lane;
            const int row  = slot >> 3;
            const int cg   = (slot & 7) ^ (row & 7);
            gload16(Xb + (size_t)(row0 + row) * D_MODEL + k0 + cg * 8,
                    (const char*)(As0 + buf * 8192) + (size_t)(wid * 256 + i * 64) * 16);
            gload16(W + (size_t)(lcol0 + row) * D_MODEL + k0 + cg * 8,
                    (const char*)(Bs0 + buf * 8192) + (size_t)(wid * 256 + i * 64) * 16);
        }
    };

    f32x4 acc[4][4];
#pragma unroll
    for (int i = 0; i < 4; i++)
#pragma unroll
        for (int j = 0; j < 4; j++) acc[i][j] = (f32x4){0.f, 0.f, 0.f, 0.f};

    stage(0, 0);
    int cur = 0;
#pragma unroll 1
    for (int k0 = 0; k0 < D_MODEL; k0 += 64) {
        __syncthreads();                       // buffer `cur` staged
        if (k0 + 64 < D_MODEL) stage(k0 + 64, cur ^ 1);   // in flight through
                                                          // compute below
        const __bf16* As = As0 + cur * 8192;
        const __bf16* Bs = Bs0 + cur * 8192;

        bf16x8 a2[2][4], b2[2][4];
#pragma unroll
        for (int ks = 0; ks < 2; ks++) {
#pragma unroll
            for (int i = 0; i < 4; i++) {
                const int rA = wrow * 64 + i * 16 + m;
                a2[ks][i] = load8(As + rA * 64 + (((ks * 4 + quad) ^ (rA & 7)) * 8));
                const int rB = wcol * 64 + i * 16 + m;
                b2[ks][i] = load8(Bs + rB * 64 + (((ks * 4 + quad) ^ (rB & 7)) * 8));
            }
        }
#pragma unroll
        for (int ks = 0; ks < 2; ks++)
#pragma unroll
            for (int i = 0; i < 4; i++)
#pragma unroll
                for (int j = 0; j < 4; j++)
                    acc[i][j] = MFMA16(a2[ks][i], b2[ks][j], acc[i][j]);
        cur ^= 1;
    }
    __syncthreads();   // all LDS reads done before V-path smem reuse

    if (wsel < 2) {
        // Q (pre-scaled) / K: [bh][s][dk]
        __bf16* Out = wsel ? Kb : Qb;
        const float sc = wsel ? 1.f : Q_SCALE;
#pragma unroll
        for (int i = 0; i < 4; i++) {
#pragma unroll
            for (int r = 0; r < 4; r++) {
                const int R  = row0 + wrow * 64 + i * 16 + quad * 4 + r;
                const int bb = R >> 11;
                const int s  = R & (SEQ - 1);
#pragma unroll
                for (int j = 0; j < 4; j++) {
                    const int e  = lcol0 + wcol * 64 + j * 16 + m;
                    const int h  = e >> 6;
                    const int dk = e & (D_K - 1);
                    Out[((size_t)(bb * NUM_HEADS + h) * SEQ + s) * D_K + dk] =
                        (__bf16)(acc[i][j][r] * sc);
                }
            }
        }
    } else {
        // V: transpose tile through LDS, store coalesced V^T rows.
        __bf16* Ls = (__bf16*)smem;   // [128][136]
#pragma unroll
        for (int i = 0; i < 4; i++)
#pragma unroll
            for (int r = 0; r < 4; r++)
#pragma unroll
                for (int j = 0; j < 4; j++)
                    Ls[(wcol * 64 + j * 16 + m) * 136 +
                       wrow * 64 + i * 16 + quad * 4 + r] = (__bf16)acc[i][j][r];
        __syncthreads();
        const int bb   = row0 >> 11;
        const int sloc = row0 & (SEQ - 1);
#pragma unroll
        for (int i = 0; i < 8; i++) {
            const int c   = i * 256 + threadIdx.x;
            const int dkl = c >> 4;
            const int sc  = c & 15;
            const bf16x8 v = load8(Ls + dkl * 136 + sc * 8);
            const int e  = lcol0 + dkl;
            const int h  = e >> 6;
            const int dk = e & (D_K - 1);
            const int bh = bb * NUM_HEADS + h;
            *reinterpret_cast<bf16x8*>(
                Vtg + ((size_t)bh * D_K + dk) * SEQ + sloc + sc * 8) = v;
        }
    }
}

// ---------------------------------------------------------------------------
// Flash attention, causal. R26: PAIR-TILE ILP on the R22 8-wave structure.
// Tiles (p, p+1) are processed between a SINGLE barrier with their two
// dependency chains interleaved -- every phase (QK MFMA, exp2/pack,
// permlane, PV MFMA) has two independent instances per wave, so the
// scheduler fills one chain's latency with the sibling's instructions.
// (Distinct from R23 unroll-2, where the barrier between copies blocked
// interleave, and from R14, which halved waves/CU.) 4-buffer LDS rotation
// (64 KB); read bufs {p&3,(p+1)&3} and write bufs {(p+2)&3,(p+3)&3} are
// disjoint; write-after-read safe (buffer (p+2)&3 last read in pair p-2).
// Causal masking generalized: mk = (t >= myDiag) -> past-diagonal tiles
// compute all-zero P (verified: t>myDiag => min key > max q), removing the
// divergent skip; extra masked MFMA only on non-critical waves.
// grid (32 bh, 16 strips) = 512 blocks x 8 waves = 16 waves/CU. T = 2sp+2
// is even -> pairs cover exactly. Register-P (zip-permlane), ones-MFMA l.
// ---------------------------------------------------------------------------
__global__ __launch_bounds__(512) void attn_kernel(
    const __bf16* __restrict__ Qb,
    const __bf16* __restrict__ Kb,
    const __bf16* __restrict__ Vtg,
    __bf16* __restrict__ Cc)
{
    __shared__ alignas(16) __bf16 Ks[4][64 * 64];  // 4-deep, 32 KB
    __shared__ alignas(16) __bf16 Vt[4][64 * 64];  // 4-deep, 32 KB

    const int lane = threadIdx.x & 63;
    const int wid  = threadIdx.x >> 6;             // 0..7
    const int m    = lane & 15;
    const int quad = lane >> 4;
    const int bh   = blockIdx.x;
    const int b    = bh >> 4;
    const int h    = bh & (NUM_HEADS - 1);
    const int sp   = 15 - blockIdx.y;              // 128-row strip, big first

    const __bf16* Qp = Qb  + (size_t)bh * SEQ * D_K;
    const __bf16* Kp = Kb  + (size_t)bh * SEQ * D_K;
    const __bf16* Vp = Vtg + (size_t)bh * D_K * SEQ;

    // staging: 64x64 K tile + 64x64 V^T tile; 512 threads cover each 8 KB
    // tile in ONE gload16 per thread per operand.
    auto stage = [&](int k0, int buf) {
        const int slot = wid * 64 + lane;
        const int row  = slot >> 3;
        const int cg   = (slot & 7) ^ (row & 7);
        gload16(Kp + (size_t)(k0 + row) * D_K + cg * 8,
                (const char*)&Ks[buf][0] + (size_t)slot * 16);
        gload16(Vp + (size_t)row * SEQ + k0 + cg * 8,
                (const char*)&Vt[buf][0] + (size_t)slot * 16);
    };

    bf16x8 vone;
#pragma unroll
    for (int e = 0; e < 8; e++) vone[e] = (__bf16)1.0f;

    const int q0     = sp * 128 + wid * 16;        // this wave's 16 q rows
    const int myDiag = q0 >> 6;                    // wave's diagonal tile
    const int T      = 2 * sp + 2;                 // tiles (EVEN, >= 2)

    const bf16x8 qB0 = load8(Qp + (size_t)(q0 + m) * D_K + quad * 8);
    const bf16x8 qB1 = load8(Qp + (size_t)(q0 + m) * D_K + 32 + quad * 8);

    f32x4 oacc[4];
#pragma unroll
    for (int c = 0; c < 4; c++) oacc[c] = (f32x4){0.f, 0.f, 0.f, 0.f};
    f32x4 accL = (f32x4){0.f, 0.f, 0.f, 0.f};      // l for q = q0+quad*4+r

    stage(0, 0);
    stage(64, 1);
#pragma unroll 1
    for (int p = 0; p < T; p += 2) {
        __syncthreads();             // tiles p, p+1 staged (issued pair p-2)
        if (p + 2 < T) stage((p + 2) * 64, (p + 2) & 3);
        if (p + 3 < T) stage((p + 3) * 64, (p + 3) & 3);

        const int k0A = p * 64, k0B = k0A + 64;
        const __bf16* KcA = &Ks[p & 3][0];
        const __bf16* KcB = &Ks[(p + 1) & 3][0];
        const __bf16* VcA = &Vt[p & 3][0];
        const __bf16* VcB = &Vt[(p + 1) & 3][0];
        const bool mkA = (p     >= myDiag);        // partial or all-zero mask
        const bool mkB = (p + 1 >= myDiag);

        // ---- QK^T for BOTH tiles, interleaved per kb; exp2; pack ----
        uint32_t w0A[4], w1A[4], w0B[4], w1B[4];
#pragma unroll
        for (int kb = 0; kb < 4; kb++) {
            const int rK = kb * 16 + m;
            const int o1 = (quad ^ (rK & 7)) * 8;
            const int o2 = ((quad + 4) ^ (rK & 7)) * 8;
            f32x4 sA = (f32x4){0.f, 0.f, 0.f, 0.f};
            sA = MFMA16(load8(KcA + rK * 64 + o1), qB0, sA);
            sA = MFMA16(load8(KcA + rK * 64 + o2), qB1, sA);
            f32x4 sB = (f32x4){0.f, 0.f, 0.f, 0.f};
            sB = MFMA16(load8(KcB + rK * 64 + o1), qB0, sB);
            sB = MFMA16(load8(KcB + rK * 64 + o2), qB1, sB);
            const int q    = q0 + m;
            const int keyA = k0A + kb * 16 + quad * 4;
            const int keyB = k0B + kb * 16 + quad * 4;
            float eA[4], eB[4];
#pragma unroll
            for (int r = 0; r < 4; r++) {
                float ea = __builtin_amdgcn_exp2f(sA[r]);
                if (mkA) ea = (keyA + r <= q) ? ea : 0.f;
                eA[r] = ea;
                float eb = __builtin_amdgcn_exp2f(sB[r]);
                if (mkB) eb = (keyB + r <= q) ? eb : 0.f;
                eB[r] = eb;
            }
            w0A[kb] = cvtpk(eA[0], eA[1]); w1A[kb] = cvtpk(eA[2], eA[3]);
            w0B[kb] = cvtpk(eB[0], eB[1]); w1B[kb] = cvtpk(eB[2], eB[3]);
        }

        // ---- zip-permlane redistribution, both tiles ----
        uint32_t a0 = w0A[0], a2 = w0A[1]; swap32(a0, a2); swap16(a0, a2);
        uint32_t a1 = w1A[0], a3 = w1A[1]; swap32(a1, a3); swap16(a1, a3);
        uint32_t a4 = w0A[2], a6 = w0A[3]; swap32(a4, a6); swap16(a4, a6);
        uint32_t a5 = w1A[2], a7 = w1A[3]; swap32(a5, a7); swap16(a5, a7);
        const bf16x8 pfAA = __builtin_bit_cast(bf16x8, (u32x4){a0, a1, a2, a3});
        const bf16x8 pfBA = __builtin_bit_cast(bf16x8, (u32x4){a4, a5, a6, a7});
        uint32_t c0 = w0B[0], c2 = w0B[1]; swap32(c0, c2); swap16(c0, c2);
        uint32_t c1 = w1B[0], c3 = w1B[1]; swap32(c1, c3); swap16(c1, c3);
        uint32_t c4 = w0B[2], c6 = w0B[3]; swap32(c4, c6); swap16(c4, c6);
        uint32_t c5 = w1B[2], c7 = w1B[3]; swap32(c5, c7); swap16(c5, c7);
        const bf16x8 pfAB = __builtin_bit_cast(bf16x8, (u32x4){c0, c1, c2, c3});
        const bf16x8 pfBB = __builtin_bit_cast(bf16x8, (u32x4){c4, c5, c6, c7});

        // ---- row-sums (ones-MFMA), both tiles ----
        accL = MFMA16(pfAA, vone, accL);
        accL = MFMA16(pfBA, vone, accL);
        accL = MFMA16(pfAB, vone, accL);
        accL = MFMA16(pfBB, vone, accL);

        // ---- P.V, both tiles interleaved per output column ----
#pragma unroll
        for (int c = 0; c < 4; c++) {
            const int rV = c * 16 + m;
            const int o1 = (quad ^ (rV & 7)) * 8;
            const int o2 = ((quad + 4) ^ (rV & 7)) * 8;
            oacc[c] = MFMA16(pfAA, load8(VcA + rV * 64 + o1), oacc[c]);
            oacc[c] = MFMA16(pfBA, load8(VcA + rV * 64 + o2), oacc[c]);
            oacc[c] = MFMA16(pfAB, load8(VcB + rV * 64 + o1), oacc[c]);
            oacc[c] = MFMA16(pfBB, load8(VcB + rV * 64 + o2), oacc[c]);
        }
    }

    // ---- epilogue: l is already per-register in accL ----
#pragma unroll
    for (int r = 0; r < 4; r++) {
        const float inv = 1.f / accL[r];
        const int srow = q0 + quad * 4 + r;
#pragma unroll
        for (int c = 0; c < 4; c++) {
            const size_t o2 = ((size_t)(b * SEQ + srow)) * D_MODEL + h * D_K + c * 16 + m;
            Cc[o2] = (__bf16)(oacc[c][r] * inv);
        }
    }
}

// ---------------------------------------------------------------------------
// Output projection (R16 config): Out = Cc * Wo^T + bo (fp32). 64x64 tile,
// grid (64,16) = 1024 blocks = 4/CU, double-buffered prefetch loop (one
// barrier per K-step), both operands via gload16 (bf16).
// ---------------------------------------------------------------------------
__global__ __launch_bounds__(256) void oproj_kernel(
    const __bf16* __restrict__ Cc,
    const __bf16* __restrict__ Wob,
    const float* __restrict__ bo,
    float* __restrict__ Out)
{
    __shared__ alignas(16) __bf16 As[2][64 * 64];  // ping-pong, 8 KB each
    __shared__ alignas(16) __bf16 Bs[2][64 * 64];  // ping-pong, 8 KB each

    const int lane = threadIdx.x & 63;
    const int wid  = threadIdx.x >> 6;
    const int m    = lane & 15;
    const int quad = lane >> 4;
    const int wrow = wid >> 1, wcol = wid & 1;
    const int row0 = blockIdx.x * 64;
    const int col0 = blockIdx.y * 64;

    auto stage = [&](int k0, int buf) {
#pragma unroll
        for (int i = 0; i < 2; i++) {
            const int slot = wid * 128 + i * 64 + lane;
            const int row  = slot >> 3;
            const int cg   = (slot & 7) ^ (row & 7);
            gload16(Cc + (size_t)(row0 + row) * D_MODEL + k0 + cg * 8,
                    (const char*)&As[buf][0] + (size_t)slot * 16);
            gload16(Wob + (size_t)(col0 + row) * D_MODEL + k0 + cg * 8,
                    (const char*)&Bs[buf][0] + (size_t)slot * 16);
        }
    };

    f32x4 acc[2][2];
#pragma unroll
    for (int i = 0; i < 2; i++)
#pragma unroll
        for (int j = 0; j < 2; j++) acc[i][j] = (f32x4){0.f, 0.f, 0.f, 0.f};

    stage(0, 0);
    int cur = 0;
#pragma unroll 1
    for (int k0 = 0; k0 < D_MODEL; k0 += 64) {
        __syncthreads();                       // buffer `cur` staged
        if (k0 + 64 < D_MODEL) stage(k0 + 64, cur ^ 1);

        bf16x8 a2[2][2], b2[2][2];
#pragma unroll
        for (int ks = 0; ks < 2; ks++) {
#pragma unroll
            for (int i = 0; i < 2; i++) {
                const int rA = wrow * 32 + i * 16 + m;
                a2[ks][i] = load8(&As[cur][0] + rA * 64 + (((ks * 4 + quad) ^ (rA & 7)) * 8));
                const int rB = wcol * 32 + i * 16 + m;
                b2[ks][i] = load8(&Bs[cur][0] + rB * 64 + (((ks * 4 + quad) ^ (rB & 7)) * 8));
            }
        }
#pragma unroll
        for (int ks = 0; ks < 2; ks++)
#pragma unroll
            for (int i = 0; i < 2; i++)
#pragma unroll
                for (int j = 0; j < 2; j++)
                    acc[i][j] = MFMA16(a2[ks][i], b2[ks][j], acc[i][j]);
        cur ^= 1;
    }

#pragma unroll
    for (int i = 0; i < 2; i++) {
#pragma unroll
        for (int r = 0; r < 4; r++) {
            const int R = row0 + wrow * 32 + i * 16 + quad * 4 + r;
#pragma unroll
            for (int j = 0; j < 2; j++) {
                const int E = col0 + wcol * 32 + j * 16 + m;
                Out[(size_t)R * D_MODEL + E] = acc[i][j][r] + bo[E];
            }
        }
    }
}

// ---------------------------------------------------------------------------
extern "C" void kernel_launch(void* const* d_in, const int* in_sizes, int n_in,
                              void* d_out, int out_size, void* d_ws, size_t ws_size,
                              hipStream_t stream) {
    const float* x  = (const float*)d_in[0];
    const float* Wq = (const float*)d_in[1];
    const float* Wk = (const float*)d_in[2];
    const float* Wv = (const float*)d_in[3];
    const float* Wo = (const float*)d_in[4];
    const float* bo = (const float*)d_in[5];
    // d_in[6] = causal mask — recomputed from indices, not read.

    const size_t elems  = (size_t)M_TOTAL * D_MODEL;   // 4194304
    const size_t welems = (size_t)D_MODEL * D_MODEL;   // 1048576
    __bf16* xb  = (__bf16*)d_ws;       // seg0: x (bf16) -> later Cc (aliased)
    __bf16* Qb  = xb + elems;
    __bf16* Kb  = Qb + elems;
    __bf16* Vtg = Kb + elems;          // [32][64][2048]  (V^T)
    __bf16* Wqb = Vtg + elems;
    __bf16* Wkb = Wqb + welems;
    __bf16* Wvb = Wkb + welems;
    __bf16* Wob = Wvb + welems;        // end: 40 MB
    __bf16* Cc  = xb;

    // 0) all fp32 -> bf16 conversions in one launch
    convert_all<<<dim3(4096), 256, 0, stream>>>(
        x, Wq, Wk, Wv, Wo, xb, Wqb, Wkb, Wvb, Wob);

    // 1) QKV projections (Q pre-scaled by 0.125*log2e), dbuf prefetch loop
    qkv_kernel<<<dim3(M_TOTAL / 128, 3 * D_MODEL / 128), 256, 0, stream>>>(
        xb, Wqb, Wkb, Wvb, Qb, Kb, Vtg);

    // 2) causal flash attention: 8-wave blocks, pair-tile ILP, 4-buffer LDS
    attn_kernel<<<dim3(BATCH * NUM_HEADS, 16), 512, 0, stream>>>(
        Qb, Kb, Vtg, Cc);

    // 3) output projection + bias -> fp32 out (64x64 tiles, dbuf prefetch)
    oproj_kernel<<<dim3(M_TOTAL / 64, D_MODEL / 64), 256, 0, stream>>>(
        Cc, Wob, bo, (float*)d_out);
}

// Round 18
// 179.321 us; speedup vs baseline: 1.0170x; 1.0170x over previous
//
#include <hip/hip_runtime.h>
#include <hip/hip_bf16.h>
#include <stdint.h>

typedef __bf16 bf16x8 __attribute__((ext_vector_type(8)));
typedef __bf16 bf16x4 __attribute__((ext_vector_type(4)));
typedef float  f32x4  __attribute__((ext_vector_type(4)));
typedef unsigned int u32x4 __attribute__((ext_vector_type(4)));

#define D_MODEL 1024
#define NUM_HEADS 16
#define D_K 64
#define BATCH 2
#define SEQ 2048
#define M_TOTAL (BATCH * SEQ)   // 4096

// 0.125 (1/sqrt(64)) * log2(e): folded into Q at the qkv epilogue so the
// attention softmax is a bare exp2 (v_exp_f32), no per-element scale mul.
#define Q_SCALE 0.18033688011112042f

static __device__ __forceinline__ bf16x8 load8(const __bf16* p) {
    return *reinterpret_cast<const bf16x8*>(p);
}

#define MFMA16(a, b, c) __builtin_amdgcn_mfma_f32_16x16x32_bf16((a), (b), (c), 0, 0, 0)

// Async global->LDS, 16B per lane. LDS dest = wave-uniform base + lane*16.
static __device__ __forceinline__ void gload16(const void* g, const void* lds) {
    __builtin_amdgcn_global_load_lds(
        (const __attribute__((address_space(1))) uint32_t*)g,
        (__attribute__((address_space(3))) uint32_t*)lds,
        16, 0, 0);
}

// Pack two f32 -> one u32 of 2 bf16 (lo = first arg). No builtin on gfx950.
static __device__ __forceinline__ uint32_t cvtpk(float lo, float hi) {
    uint32_t r;
    asm("v_cvt_pk_bf16_f32 %0, %1, %2" : "=v"(r) : "v"(lo), "v"(hi));
    return r;
}
// CDNA4 zip semantics ("DST rows 2:3 <-> SRC rows 0:1", rows = 16 lanes):
//   swap32: a' = (a@q0, a@q1, b@q0, b@q1), b' = (a@q2, a@q3, b@q2, b@q3)
static __device__ __forceinline__ void swap32(uint32_t& a, uint32_t& b) {
    asm("v_permlane32_swap_b32 %0, %1" : "+v"(a), "+v"(b));
}
// swap16 ("DST odd rows <-> SRC even rows"):
//   a' = (a@q0, b@q0, a@q2, b@q2), b' = (a@q1, b@q1, a@q3, b@q3)
static __device__ __forceinline__ void swap16(uint32_t& a, uint32_t& b) {
    asm("v_permlane16_swap_b32 %0, %1" : "+v"(a), "+v"(b));
}

// ---------------------------------------------------------------------------
// One launch: x (2048 blocks) + 4 weight matrices (512 blocks each) fp32->bf16.
// ---------------------------------------------------------------------------
__global__ __launch_bounds__(256) void convert_all(
    const float* __restrict__ X,
    const float* __restrict__ Wq, const float* __restrict__ Wk,
    const float* __restrict__ Wv, const float* __restrict__ Wo,
    __bf16* __restrict__ xb,
    __bf16* __restrict__ dq, __bf16* __restrict__ dk,
    __bf16* __restrict__ dv, __bf16* __restrict__ dw)
{
    const float* src; __bf16* dst; size_t idx;
    if (blockIdx.x < 2048) {
        src = X; dst = xb;
        idx = (size_t)blockIdx.x * 256 + threadIdx.x;
    } else {
        const int wb  = blockIdx.x - 2048;
        const int sel = wb >> 9;
        src = (sel == 0) ? Wq : (sel == 1) ? Wk : (sel == 2) ? Wv : Wo;
        dst = (sel == 0) ? dq : (sel == 1) ? dk : (sel == 2) ? dv : dw;
        idx = (size_t)(wb & 511) * 256 + threadIdx.x;
    }
    const f32x4 a = *reinterpret_cast<const f32x4*>(src + idx * 8);
    const f32x4 b = *reinterpret_cast<const f32x4*>(src + idx * 8 + 4);
    bf16x8 r;
#pragma unroll
    for (int e = 0; e < 4; e++) { r[e] = (__bf16)a[e]; r[4 + e] = (__bf16)b[e]; }
    *reinterpret_cast<bf16x8*>(dst + idx * 8) = r;
}

// ---------------------------------------------------------------------------
// QKV GEMM (R16 config): 128x128 tile, BK=64, swizzled gload16 staging,
// double-buffered prefetch loop (one barrier per K-step, next tile's loads
// in flight through compute). LDS 64 KB -> 2 blocks/CU. Q output pre-scaled
// by Q_SCALE. V transposed through LDS -> V^T. grid = (32, 24), block = 256.
// ---------------------------------------------------------------------------
__global__ __launch_bounds__(256) void qkv_kernel(
    const __bf16* __restrict__ Xb,
    const __bf16* __restrict__ Wqb,
    const __bf16* __restrict__ Wkb,
    const __bf16* __restrict__ Wvb,
    __bf16* __restrict__ Qb,
    __bf16* __restrict__ Kb,
    __bf16* __restrict__ Vtg)
{
    __shared__ alignas(16) char smem[65536];   // A[2]16K + B[2]16K; V scratch 34K
    __bf16* As0 = (__bf16*)smem;               // [2][128*64], chunk-swizzled
    __bf16* Bs0 = As0 + 2 * 128 * 64;

    const int lane = threadIdx.x & 63;
    const int wid  = threadIdx.x >> 6;
    const int m    = lane & 15;
    const int quad = lane >> 4;
    const int wrow = wid >> 1, wcol = wid & 1;
    const int row0 = blockIdx.x * 128;
    const int col0 = blockIdx.y * 128;
    const int wsel = col0 >> 10;
    const int lcol0 = col0 & 1023;

    const __bf16* W = (wsel == 0) ? Wqb : (wsel == 1) ? Wkb : Wvb;

    // staging: 128x64 A-tile + 128x64 B-tile into buffer `buf`
    auto stage = [&](int k0, int buf) {
#pragma unroll
        for (int i = 0; i < 4; i++) {
            const int slot = wid * 256 + i * 64 + lane;
            const int row  = slot >> 3;
            const int cg   = (slot & 7) ^ (row & 7);
            gload16(Xb + (size_t)(row0 + row) * D_MODEL + k0 + cg * 8,
                    (const char*)(As0 + buf * 8192) + (size_t)(wid * 256 + i * 64) * 16);
            gload16(W + (size_t)(lcol0 + row) * D_MODEL + k0 + cg * 8,
                    (const char*)(Bs0 + buf * 8192) + (size_t)(wid * 256 + i * 64) * 16);
        }
    };

    f32x4 acc[4][4];
#pragma unroll
    for (int i = 0; i < 4; i++)
#pragma unroll
        for (int j = 0; j < 4; j++) acc[i][j] = (f32x4){0.f, 0.f, 0.f, 0.f};

    stage(0, 0);
    int cur = 0;
#pragma unroll 1
    for (int k0 = 0; k0 < D_MODEL; k0 += 64) {
        __syncthreads();                       // buffer `cur` staged
        if (k0 + 64 < D_MODEL) stage(k0 + 64, cur ^ 1);   // in flight through
                                                          // compute below
        const __bf16* As = As0 + cur * 8192;
        const __bf16* Bs = Bs0 + cur * 8192;

        bf16x8 a2[2][4], b2[2][4];
#pragma unroll
        for (int ks = 0; ks < 2; ks++) {
#pragma unroll
            for (int i = 0; i < 4; i++) {
                const int rA = wrow * 64 + i * 16 + m;
                a2[ks][i] = load8(As + rA * 64 + (((ks * 4 + quad) ^ (rA & 7)) * 8));
                const int rB = wcol * 64 + i * 16 + m;
                b2[ks][i] = load8(Bs + rB * 64 + (((ks * 4 + quad) ^ (rB & 7)) * 8));
            }
        }
#pragma unroll
        for (int ks = 0; ks < 2; ks++)
#pragma unroll
            for (int i = 0; i < 4; i++)
#pragma unroll
                for (int j = 0; j < 4; j++)
                    acc[i][j] = MFMA16(a2[ks][i], b2[ks][j], acc[i][j]);
        cur ^= 1;
    }
    __syncthreads();   // all LDS reads done before V-path smem reuse

    if (wsel < 2) {
        // Q (pre-scaled) / K: [bh][s][dk]
        __bf16* Out = wsel ? Kb : Qb;
        const float sc = wsel ? 1.f : Q_SCALE;
#pragma unroll
        for (int i = 0; i < 4; i++) {
#pragma unroll
            for (int r = 0; r < 4; r++) {
                const int R  = row0 + wrow * 64 + i * 16 + quad * 4 + r;
                const int bb = R >> 11;
                const int s  = R & (SEQ - 1);
#pragma unroll
                for (int j = 0; j < 4; j++) {
                    const int e  = lcol0 + wcol * 64 + j * 16 + m;
                    const int h  = e >> 6;
                    const int dk = e & (D_K - 1);
                    Out[((size_t)(bb * NUM_HEADS + h) * SEQ + s) * D_K + dk] =
                        (__bf16)(acc[i][j][r] * sc);
                }
            }
        }
    } else {
        // V: transpose tile through LDS, store coalesced V^T rows.
        __bf16* Ls = (__bf16*)smem;   // [128][136]
#pragma unroll
        for (int i = 0; i < 4; i++)
#pragma unroll
            for (int r = 0; r < 4; r++)
#pragma unroll
                for (int j = 0; j < 4; j++)
                    Ls[(wcol * 64 + j * 16 + m) * 136 +
                       wrow * 64 + i * 16 + quad * 4 + r] = (__bf16)acc[i][j][r];
        __syncthreads();
        const int bb   = row0 >> 11;
        const int sloc = row0 & (SEQ - 1);
#pragma unroll
        for (int i = 0; i < 8; i++) {
            const int c   = i * 256 + threadIdx.x;
            const int dkl = c >> 4;
            const int sc  = c & 15;
            const bf16x8 v = load8(Ls + dkl * 136 + sc * 8);
            const int e  = lcol0 + dkl;
            const int h  = e >> 6;
            const int dk = e & (D_K - 1);
            const int bh = bb * NUM_HEADS + h;
            *reinterpret_cast<bf16x8*>(
                Vtg + ((size_t)bh * D_K + dk) * SEQ + sloc + sc * 8) = v;
        }
    }
}

// ---------------------------------------------------------------------------
// Flash attention, causal (FINAL: R26 pair-tile ILP, session-best attn
// per-dispatch <= 41.4 us). Tiles (p, p+1) processed between a SINGLE
// barrier with their two dependency chains interleaved -- every phase
// (QK MFMA, exp2/pack, permlane, PV MFMA) has two independent instances
// per wave, so the scheduler fills one chain's latency with the sibling's
// instructions. 4-buffer LDS rotation (64 KB); read bufs {p&3,(p+1)&3} and
// write bufs {(p+2)&3,(p+3)&3} disjoint; write-after-read safe. Causal
// mask mk = (t >= myDiag): past-diagonal tiles compute all-zero P
// (t>myDiag => min key > max q), no divergent skips. grid (32 bh, 16
// strips) = 512 blocks x 8 waves = 16 waves/CU. T = 2sp+2 even -> pairs
// cover exactly. Register-P (zip-permlane), ones-MFMA row sums.
// ---------------------------------------------------------------------------
__global__ __launch_bounds__(512) void attn_kernel(
    const __bf16* __restrict__ Qb,
    const __bf16* __restrict__ Kb,
    const __bf16* __restrict__ Vtg,
    __bf16* __restrict__ Cc)
{
    __shared__ alignas(16) __bf16 Ks[4][64 * 64];  // 4-deep, 32 KB
    __shared__ alignas(16) __bf16 Vt[4][64 * 64];  // 4-deep, 32 KB

    const int lane = threadIdx.x & 63;
    const int wid  = threadIdx.x >> 6;             // 0..7
    const int m    = lane & 15;
    const int quad = lane >> 4;
    const int bh   = blockIdx.x;
    const int b    = bh >> 4;
    const int h    = bh & (NUM_HEADS - 1);
    const int sp   = 15 - blockIdx.y;              // 128-row strip, big first

    const __bf16* Qp = Qb  + (size_t)bh * SEQ * D_K;
    const __bf16* Kp = Kb  + (size_t)bh * SEQ * D_K;
    const __bf16* Vp = Vtg + (size_t)bh * D_K * SEQ;

    // staging: 64x64 K tile + 64x64 V^T tile; 512 threads cover each 8 KB
    // tile in ONE gload16 per thread per operand.
    auto stage = [&](int k0, int buf) {
        const int slot = wid * 64 + lane;
        const int row  = slot >> 3;
        const int cg   = (slot & 7) ^ (row & 7);
        gload16(Kp + (size_t)(k0 + row) * D_K + cg * 8,
                (const char*)&Ks[buf][0] + (size_t)slot * 16);
        gload16(Vp + (size_t)row * SEQ + k0 + cg * 8,
                (const char*)&Vt[buf][0] + (size_t)slot * 16);
    };

    bf16x8 vone;
#pragma unroll
    for (int e = 0; e < 8; e++) vone[e] = (__bf16)1.0f;

    const int q0     = sp * 128 + wid * 16;        // this wave's 16 q rows
    const int myDiag = q0 >> 6;                    // wave's diagonal tile
    const int T      = 2 * sp + 2;                 // tiles (EVEN, >= 2)

    const bf16x8 qB0 = load8(Qp + (size_t)(q0 + m) * D_K + quad * 8);
    const bf16x8 qB1 = load8(Qp + (size_t)(q0 + m) * D_K + 32 + quad * 8);

    f32x4 oacc[4];
#pragma unroll
    for (int c = 0; c < 4; c++) oacc[c] = (f32x4){0.f, 0.f, 0.f, 0.f};
    f32x4 accL = (f32x4){0.f, 0.f, 0.f, 0.f};      // l for q = q0+quad*4+r

    stage(0, 0);
    stage(64, 1);
#pragma unroll 1
    for (int p = 0; p < T; p += 2) {
        __syncthreads();             // tiles p, p+1 staged (issued pair p-2)
        if (p + 2 < T) stage((p + 2) * 64, (p + 2) & 3);
        if (p + 3 < T) stage((p + 3) * 64, (p + 3) & 3);

        const int k0A = p * 64, k0B = k0A + 64;
        const __bf16* KcA = &Ks[p & 3][0];
        const __bf16* KcB = &Ks[(p + 1) & 3][0];
        const __bf16* VcA = &Vt[p & 3][0];
        const __bf16* VcB = &Vt[(p + 1) & 3][0];
        const bool mkA = (p     >= myDiag);        // partial or all-zero mask
        const bool mkB = (p + 1 >= myDiag);

        // ---- QK^T for BOTH tiles, interleaved per kb; exp2; pack ----
        uint32_t w0A[4], w1A[4], w0B[4], w1B[4];
#pragma unroll
        for (int kb = 0; kb < 4; kb++) {
            const int rK = kb * 16 + m;
            const int o1 = (quad ^ (rK & 7)) * 8;
            const int o2 = ((quad + 4) ^ (rK & 7)) * 8;
            f32x4 sA = (f32x4){0.f, 0.f, 0.f, 0.f};
            sA = MFMA16(load8(KcA + rK * 64 + o1), qB0, sA);
            sA = MFMA16(load8(KcA + rK * 64 + o2), qB1, sA);
            f32x4 sB = (f32x4){0.f, 0.f, 0.f, 0.f};
            sB = MFMA16(load8(KcB + rK * 64 + o1), qB0, sB);
            sB = MFMA16(load8(KcB + rK * 64 + o2), qB1, sB);
            const int q    = q0 + m;
            const int keyA = k0A + kb * 16 + quad * 4;
            const int keyB = k0B + kb * 16 + quad * 4;
            float eA[4], eB[4];
#pragma unroll
            for (int r = 0; r < 4; r++) {
                float ea = __builtin_amdgcn_exp2f(sA[r]);
                if (mkA) ea = (keyA + r <= q) ? ea : 0.f;
                eA[r] = ea;
                float eb = __builtin_amdgcn_exp2f(sB[r]);
                if (mkB) eb = (keyB + r <= q) ? eb : 0.f;
                eB[r] = eb;
            }
            w0A[kb] = cvtpk(eA[0], eA[1]); w1A[kb] = cvtpk(eA[2], eA[3]);
            w0B[kb] = cvtpk(eB[0], eB[1]); w1B[kb] = cvtpk(eB[2], eB[3]);
        }

        // ---- zip-permlane redistribution, both tiles ----
        uint32_t a0 = w0A[0], a2 = w0A[1]; swap32(a0, a2); swap16(a0, a2);
        uint32_t a1 = w1A[0], a3 = w1A[1]; swap32(a1, a3); swap16(a1, a3);
        uint32_t a4 = w0A[2], a6 = w0A[3]; swap32(a4, a6); swap16(a4, a6);
        uint32_t a5 = w1A[2], a7 = w1A[3]; swap32(a5, a7); swap16(a5, a7);
        const bf16x8 pfAA = __builtin_bit_cast(bf16x8, (u32x4){a0, a1, a2, a3});
        const bf16x8 pfBA = __builtin_bit_cast(bf16x8, (u32x4){a4, a5, a6, a7});
        uint32_t c0 = w0B[0], c2 = w0B[1]; swap32(c0, c2); swap16(c0, c2);
        uint32_t c1 = w1B[0], c3 = w1B[1]; swap32(c1, c3); swap16(c1, c3);
        uint32_t c4 = w0B[2], c6 = w0B[3]; swap32(c4, c6); swap16(c4, c6);
        uint32_t c5 = w1B[2], c7 = w1B[3]; swap32(c5, c7); swap16(c5, c7);
        const bf16x8 pfAB = __builtin_bit_cast(bf16x8, (u32x4){c0, c1, c2, c3});
        const bf16x8 pfBB = __builtin_bit_cast(bf16x8, (u32x4){c4, c5, c6, c7});

        // ---- row-sums (ones-MFMA), both tiles ----
        accL = MFMA16(pfAA, vone, accL);
        accL = MFMA16(pfBA, vone, accL);
        accL = MFMA16(pfAB, vone, accL);
        accL = MFMA16(pfBB, vone, accL);

        // ---- P.V, both tiles interleaved per output column ----
#pragma unroll
        for (int c = 0; c < 4; c++) {
            const int rV = c * 16 + m;
            const int o1 = (quad ^ (rV & 7)) * 8;
            const int o2 = ((quad + 4) ^ (rV & 7)) * 8;
            oacc[c] = MFMA16(pfAA, load8(VcA + rV * 64 + o1), oacc[c]);
            oacc[c] = MFMA16(pfBA, load8(VcA + rV * 64 + o2), oacc[c]);
            oacc[c] = MFMA16(pfAB, load8(VcB + rV * 64 + o1), oacc[c]);
            oacc[c] = MFMA16(pfBB, load8(VcB + rV * 64 + o2), oacc[c]);
        }
    }

    // ---- epilogue: l is already per-register in accL ----
#pragma unroll
    for (int r = 0; r < 4; r++) {
        const float inv = 1.f / accL[r];
        const int srow = q0 + quad * 4 + r;
#pragma unroll
        for (int c = 0; c < 4; c++) {
            const size_t o2 = ((size_t)(b * SEQ + srow)) * D_MODEL + h * D_K + c * 16 + m;
            Cc[o2] = (__bf16)(oacc[c][r] * inv);
        }
    }
}

// ---------------------------------------------------------------------------
// Output projection (R16 config): Out = Cc * Wo^T + bo (fp32). 64x64 tile,
// grid (64,16) = 1024 blocks = 4/CU, double-buffered prefetch loop (one
// barrier per K-step), both operands via gload16 (bf16).
// ---------------------------------------------------------------------------
__global__ __launch_bounds__(256) void oproj_kernel(
    const __bf16* __restrict__ Cc,
    const __bf16* __restrict__ Wob,
    const float* __restrict__ bo,
    float* __restrict__ Out)
{
    __shared__ alignas(16) __bf16 As[2][64 * 64];  // ping-pong, 8 KB each
    __shared__ alignas(16) __bf16 Bs[2][64 * 64];  // ping-pong, 8 KB each

    const int lane = threadIdx.x & 63;
    const int wid  = threadIdx.x >> 6;
    const int m    = lane & 15;
    const int quad = lane >> 4;
    const int wrow = wid >> 1, wcol = wid & 1;
    const int row0 = blockIdx.x * 64;
    const int col0 = blockIdx.y * 64;

    auto stage = [&](int k0, int buf) {
#pragma unroll
        for (int i = 0; i < 2; i++) {
            const int slot = wid * 128 + i * 64 + lane;
            const int row  = slot >> 3;
            const int cg   = (slot & 7) ^ (row & 7);
            gload16(Cc + (size_t)(row0 + row) * D_MODEL + k0 + cg * 8,
                    (const char*)&As[buf][0] + (size_t)slot * 16);
            gload16(Wob + (size_t)(col0 + row) * D_MODEL + k0 + cg * 8,
                    (const char*)&Bs[buf][0] + (size_t)slot * 16);
        }
    };

    f32x4 acc[2][2];
#pragma unroll
    for (int i = 0; i < 2; i++)
#pragma unroll
        for (int j = 0; j < 2; j++) acc[i][j] = (f32x4){0.f, 0.f, 0.f, 0.f};

    stage(0, 0);
    int cur = 0;
#pragma unroll 1
    for (int k0 = 0; k0 < D_MODEL; k0 += 64) {
        __syncthreads();                       // buffer `cur` staged
        if (k0 + 64 < D_MODEL) stage(k0 + 64, cur ^ 1);

        bf16x8 a2[2][2], b2[2][2];
#pragma unroll
        for (int ks = 0; ks < 2; ks++) {
#pragma unroll
            for (int i = 0; i < 2; i++) {
                const int rA = wrow * 32 + i * 16 + m;
                a2[ks][i] = load8(&As[cur][0] + rA * 64 + (((ks * 4 + quad) ^ (rA & 7)) * 8));
                const int rB = wcol * 32 + i * 16 + m;
                b2[ks][i] = load8(&Bs[cur][0] + rB * 64 + (((ks * 4 + quad) ^ (rB & 7)) * 8));
            }
        }
#pragma unroll
        for (int ks = 0; ks < 2; ks++)
#pragma unroll
            for (int i = 0; i < 2; i++)
#pragma unroll
                for (int j = 0; j < 2; j++)
                    acc[i][j] = MFMA16(a2[ks][i], b2[ks][j], acc[i][j]);
        cur ^= 1;
    }

#pragma unroll
    for (int i = 0; i < 2; i++) {
#pragma unroll
        for (int r = 0; r < 4; r++) {
            const int R = row0 + wrow * 32 + i * 16 + quad * 4 + r;
#pragma unroll
            for (int j = 0; j < 2; j++) {
                const int E = col0 + wcol * 32 + j * 16 + m;
                Out[(size_t)R * D_MODEL + E] = acc[i][j][r] + bo[E];
            }
        }
    }
}

// ---------------------------------------------------------------------------
extern "C" void kernel_launch(void* const* d_in, const int* in_sizes, int n_in,
                              void* d_out, int out_size, void* d_ws, size_t ws_size,
                              hipStream_t stream) {
    const float* x  = (const float*)d_in[0];
    const float* Wq = (const float*)d_in[1];
    const float* Wk = (const float*)d_in[2];
    const float* Wv = (const float*)d_in[3];
    const float* Wo = (const float*)d_in[4];
    const float* bo = (const float*)d_in[5];
    // d_in[6] = causal mask — recomputed from indices, not read.

    const size_t elems  = (size_t)M_TOTAL * D_MODEL;   // 4194304
    const size_t welems = (size_t)D_MODEL * D_MODEL;   // 1048576
    __bf16* xb  = (__bf16*)d_ws;       // seg0: x (bf16) -> later Cc (aliased)
    __bf16* Qb  = xb + elems;
    __bf16* Kb  = Qb + elems;
    __bf16* Vtg = Kb + elems;          // [32][64][2048]  (V^T)
    __bf16* Wqb = Vtg + elems;
    __bf16* Wkb = Wqb + welems;
    __bf16* Wvb = Wkb + welems;
    __bf16* Wob = Wvb + welems;        // end: 40 MB
    __bf16* Cc  = xb;

    // 0) all fp32 -> bf16 conversions in one launch
    convert_all<<<dim3(4096), 256, 0, stream>>>(
        x, Wq, Wk, Wv, Wo, xb, Wqb, Wkb, Wvb, Wob);

    // 1) QKV projections (Q pre-scaled by 0.125*log2e), dbuf prefetch loop
    qkv_kernel<<<dim3(M_TOTAL / 128, 3 * D_MODEL / 128), 256, 0, stream>>>(
        xb, Wqb, Wkb, Wvb, Qb, Kb, Vtg);

    // 2) causal flash attention: 8-wave blocks, pair-tile ILP, 4-buffer LDS
    attn_kernel<<<dim3(BATCH * NUM_HEADS, 16), 512, 0, stream>>>(
        Qb, Kb, Vtg, Cc);

    // 3) output projection + bias -> fp32 out (64x64 tiles, dbuf prefetch)
    oproj_kernel<<<dim3(M_TOTAL / 64, D_MODEL / 64), 256, 0, stream>>>(
        Cc, Wob, bo, (float*)d_out);
}

// Round 19
// 172.381 us; speedup vs baseline: 1.0580x; 1.0403x over previous
//
#include <hip/hip_runtime.h>
#include <hip/hip_bf16.h>
#include <stdint.h>

typedef __bf16 bf16x8 __attribute__((ext_vector_type(8)));
typedef __bf16 bf16x4 __attribute__((ext_vector_type(4)));
typedef float  f32x4  __attribute__((ext_vector_type(4)));
typedef unsigned int u32x4 __attribute__((ext_vector_type(4)));

#define D_MODEL 1024
#define NUM_HEADS 16
#define D_K 64
#define BATCH 2
#define SEQ 2048
#define M_TOTAL (BATCH * SEQ)   // 4096

// 0.125 (1/sqrt(64)) * log2(e): folded into Q at the qkv epilogue so the
// attention softmax is a bare exp2 (v_exp_f32), no per-element scale mul.
#define Q_SCALE 0.18033688011112042f

static __device__ __forceinline__ bf16x8 load8(const __bf16* p) {
    return *reinterpret_cast<const bf16x8*>(p);
}

#define MFMA16(a, b, c) __builtin_amdgcn_mfma_f32_16x16x32_bf16((a), (b), (c), 0, 0, 0)

// Async global->LDS, 16B per lane. LDS dest = wave-uniform base + lane*16.
static __device__ __forceinline__ void gload16(const void* g, const void* lds) {
    __builtin_amdgcn_global_load_lds(
        (const __attribute__((address_space(1))) uint32_t*)g,
        (__attribute__((address_space(3))) uint32_t*)lds,
        16, 0, 0);
}

// Pack two f32 -> one u32 of 2 bf16 (lo = first arg). No builtin on gfx950.
static __device__ __forceinline__ uint32_t cvtpk(float lo, float hi) {
    uint32_t r;
    asm("v_cvt_pk_bf16_f32 %0, %1, %2" : "=v"(r) : "v"(lo), "v"(hi));
    return r;
}
// CDNA4 zip semantics ("DST rows 2:3 <-> SRC rows 0:1", rows = 16 lanes):
//   swap32: a' = (a@q0, a@q1, b@q0, b@q1), b' = (a@q2, a@q3, b@q2, b@q3)
static __device__ __forceinline__ void swap32(uint32_t& a, uint32_t& b) {
    asm("v_permlane32_swap_b32 %0, %1" : "+v"(a), "+v"(b));
}
// swap16 ("DST odd rows <-> SRC even rows"):
//   a' = (a@q0, b@q0, a@q2, b@q2), b' = (a@q1, b@q1, a@q3, b@q3)
static __device__ __forceinline__ void swap16(uint32_t& a, uint32_t& b) {
    asm("v_permlane16_swap_b32 %0, %1" : "+v"(a), "+v"(b));
}

// ---------------------------------------------------------------------------
// One launch: x (2048 blocks) + 4 weight matrices (512 blocks each) fp32->bf16.
// ---------------------------------------------------------------------------
__global__ __launch_bounds__(256) void convert_all(
    const float* __restrict__ X,
    const float* __restrict__ Wq, const float* __restrict__ Wk,
    const float* __restrict__ Wv, const float* __restrict__ Wo,
    __bf16* __restrict__ xb,
    __bf16* __restrict__ dq, __bf16* __restrict__ dk,
    __bf16* __restrict__ dv, __bf16* __restrict__ dw)
{
    const float* src; __bf16* dst; size_t idx;
    if (blockIdx.x < 2048) {
        src = X; dst = xb;
        idx = (size_t)blockIdx.x * 256 + threadIdx.x;
    } else {
        const int wb  = blockIdx.x - 2048;
        const int sel = wb >> 9;
        src = (sel == 0) ? Wq : (sel == 1) ? Wk : (sel == 2) ? Wv : Wo;
        dst = (sel == 0) ? dq : (sel == 1) ? dk : (sel == 2) ? dv : dw;
        idx = (size_t)(wb & 511) * 256 + threadIdx.x;
    }
    const f32x4 a = *reinterpret_cast<const f32x4*>(src + idx * 8);
    const f32x4 b = *reinterpret_cast<const f32x4*>(src + idx * 8 + 4);
    bf16x8 r;
#pragma unroll
    for (int e = 0; e < 4; e++) { r[e] = (__bf16)a[e]; r[4 + e] = (__bf16)b[e]; }
    *reinterpret_cast<bf16x8*>(dst + idx * 8) = r;
}

// ---------------------------------------------------------------------------
// QKV GEMM (R16 config): 128x128 tile, BK=64, swizzled gload16 staging,
// double-buffered prefetch loop (one barrier per K-step, next tile's loads
// in flight through compute). LDS 64 KB -> 2 blocks/CU. Q output pre-scaled
// by Q_SCALE. V transposed through LDS -> V^T. grid = (32, 24), block = 256.
// ---------------------------------------------------------------------------
__global__ __launch_bounds__(256) void qkv_kernel(
    const __bf16* __restrict__ Xb,
    const __bf16* __restrict__ Wqb,
    const __bf16* __restrict__ Wkb,
    const __bf16* __restrict__ Wvb,
    __bf16* __restrict__ Qb,
    __bf16* __restrict__ Kb,
    __bf16* __restrict__ Vtg)
{
    __shared__ alignas(16) char smem[65536];   // A[2]16K + B[2]16K; V scratch 34K
    __bf16* As0 = (__bf16*)smem;               // [2][128*64], chunk-swizzled
    __bf16* Bs0 = As0 + 2 * 128 * 64;

    const int lane = threadIdx.x & 63;
    const int wid  = threadIdx.x >> 6;
    const int m    = lane & 15;
    const int quad = lane >> 4;
    const int wrow = wid >> 1, wcol = wid & 1;
    const int row0 = blockIdx.x * 128;
    const int col0 = blockIdx.y * 128;
    const int wsel = col0 >> 10;
    const int lcol0 = col0 & 1023;

    const __bf16* W = (wsel == 0) ? Wqb : (wsel == 1) ? Wkb : Wvb;

    // staging: 128x64 A-tile + 128x64 B-tile into buffer `buf`
    auto stage = [&](int k0, int buf) {
#pragma unroll
        for (int i = 0; i < 4; i++) {
            const int slot = wid * 256 + i * 64 + lane;
            const int row  = slot >> 3;
            const int cg   = (slot & 7) ^ (row & 7);
            gload16(Xb + (size_t)(row0 + row) * D_MODEL + k0 + cg * 8,
                    (const char*)(As0 + buf * 8192) + (size_t)(wid * 256 + i * 64) * 16);
            gload16(W + (size_t)(lcol0 + row) * D_MODEL + k0 + cg * 8,
                    (const char*)(Bs0 + buf * 8192) + (size_t)(wid * 256 + i * 64) * 16);
        }
    };

    f32x4 acc[4][4];
#pragma unroll
    for (int i = 0; i < 4; i++)
#pragma unroll
        for (int j = 0; j < 4; j++) acc[i][j] = (f32x4){0.f, 0.f, 0.f, 0.f};

    stage(0, 0);
    int cur = 0;
#pragma unroll 1
    for (int k0 = 0; k0 < D_MODEL; k0 += 64) {
        __syncthreads();                       // buffer `cur` staged
        if (k0 + 64 < D_MODEL) stage(k0 + 64, cur ^ 1);   // in flight through
                                                          // compute below
        const __bf16* As = As0 + cur * 8192;
        const __bf16* Bs = Bs0 + cur * 8192;

        bf16x8 a2[2][4], b2[2][4];
#pragma unroll
        for (int ks = 0; ks < 2; ks++) {
#pragma unroll
            for (int i = 0; i < 4; i++) {
                const int rA = wrow * 64 + i * 16 + m;
                a2[ks][i] = load8(As + rA * 64 + (((ks * 4 + quad) ^ (rA & 7)) * 8));
                const int rB = wcol * 64 + i * 16 + m;
                b2[ks][i] = load8(Bs + rB * 64 + (((ks * 4 + quad) ^ (rB & 7)) * 8));
            }
        }
#pragma unroll
        for (int ks = 0; ks < 2; ks++)
#pragma unroll
            for (int i = 0; i < 4; i++)
#pragma unroll
                for (int j = 0; j < 4; j++)
                    acc[i][j] = MFMA16(a2[ks][i], b2[ks][j], acc[i][j]);
        cur ^= 1;
    }
    __syncthreads();   // all LDS reads done before V-path smem reuse

    if (wsel < 2) {
        // Q (pre-scaled) / K: [bh][s][dk]
        __bf16* Out = wsel ? Kb : Qb;
        const float sc = wsel ? 1.f : Q_SCALE;
#pragma unroll
        for (int i = 0; i < 4; i++) {
#pragma unroll
            for (int r = 0; r < 4; r++) {
                const int R  = row0 + wrow * 64 + i * 16 + quad * 4 + r;
                const int bb = R >> 11;
                const int s  = R & (SEQ - 1);
#pragma unroll
                for (int j = 0; j < 4; j++) {
                    const int e  = lcol0 + wcol * 64 + j * 16 + m;
                    const int h  = e >> 6;
                    const int dk = e & (D_K - 1);
                    Out[((size_t)(bb * NUM_HEADS + h) * SEQ + s) * D_K + dk] =
                        (__bf16)(acc[i][j][r] * sc);
                }
            }
        }
    } else {
        // V: transpose tile through LDS, store coalesced V^T rows.
        __bf16* Ls = (__bf16*)smem;   // [128][136]
#pragma unroll
        for (int i = 0; i < 4; i++)
#pragma unroll
            for (int r = 0; r < 4; r++)
#pragma unroll
                for (int j = 0; j < 4; j++)
                    Ls[(wcol * 64 + j * 16 + m) * 136 +
                       wrow * 64 + i * 16 + quad * 4 + r] = (__bf16)acc[i][j][r];
        __syncthreads();
        const int bb   = row0 >> 11;
        const int sloc = row0 & (SEQ - 1);
#pragma unroll
        for (int i = 0; i < 8; i++) {
            const int c   = i * 256 + threadIdx.x;
            const int dkl = c >> 4;
            const int sc  = c & 15;
            const bf16x8 v = load8(Ls + dkl * 136 + sc * 8);
            const int e  = lcol0 + dkl;
            const int h  = e >> 6;
            const int dk = e & (D_K - 1);
            const int bh = bb * NUM_HEADS + h;
            *reinterpret_cast<bf16x8*>(
                Vtg + ((size_t)bh * D_K + dk) * SEQ + sloc + sc * 8) = v;
        }
    }
}

// ---------------------------------------------------------------------------
// Flash attention, causal (FINAL, confirmed twice: attn 42.7-43.0 us/disp).
// R26 pair-tile ILP: tiles (p, p+1) processed between a SINGLE barrier with
// their two dependency chains interleaved -- every phase (QK MFMA,
// exp2/pack, permlane, PV MFMA) has two independent instances per wave, so
// the scheduler fills one chain's latency with the sibling's instructions.
// 4-buffer LDS rotation (64 KB); read bufs {p&3,(p+1)&3} and write bufs
// {(p+2)&3,(p+3)&3} disjoint; write-after-read safe. Causal mask
// mk = (t >= myDiag): past-diagonal tiles compute all-zero P, no divergent
// skips (only 1 wasted tile on waves 0-3). grid (32 bh, 16 strips) = 512
// blocks x 8 waves = 16 waves/CU. T = 2sp+2 even -> pairs cover exactly.
// Register-P (zip-permlane), ones-MFMA row sums.
// ---------------------------------------------------------------------------
__global__ __launch_bounds__(512) void attn_kernel(
    const __bf16* __restrict__ Qb,
    const __bf16* __restrict__ Kb,
    const __bf16* __restrict__ Vtg,
    __bf16* __restrict__ Cc)
{
    __shared__ alignas(16) __bf16 Ks[4][64 * 64];  // 4-deep, 32 KB
    __shared__ alignas(16) __bf16 Vt[4][64 * 64];  // 4-deep, 32 KB

    const int lane = threadIdx.x & 63;
    const int wid  = threadIdx.x >> 6;             // 0..7
    const int m    = lane & 15;
    const int quad = lane >> 4;
    const int bh   = blockIdx.x;
    const int b    = bh >> 4;
    const int h    = bh & (NUM_HEADS - 1);
    const int sp   = 15 - blockIdx.y;              // 128-row strip, big first

    const __bf16* Qp = Qb  + (size_t)bh * SEQ * D_K;
    const __bf16* Kp = Kb  + (size_t)bh * SEQ * D_K;
    const __bf16* Vp = Vtg + (size_t)bh * D_K * SEQ;

    // staging: 64x64 K tile + 64x64 V^T tile; 512 threads cover each 8 KB
    // tile in ONE gload16 per thread per operand.
    auto stage = [&](int k0, int buf) {
        const int slot = wid * 64 + lane;
        const int row  = slot >> 3;
        const int cg   = (slot & 7) ^ (row & 7);
        gload16(Kp + (size_t)(k0 + row) * D_K + cg * 8,
                (const char*)&Ks[buf][0] + (size_t)slot * 16);
        gload16(Vp + (size_t)row * SEQ + k0 + cg * 8,
                (const char*)&Vt[buf][0] + (size_t)slot * 16);
    };

    bf16x8 vone;
#pragma unroll
    for (int e = 0; e < 8; e++) vone[e] = (__bf16)1.0f;

    const int q0     = sp * 128 + wid * 16;        // this wave's 16 q rows
    const int myDiag = q0 >> 6;                    // wave's diagonal tile
    const int T      = 2 * sp + 2;                 // tiles (EVEN, >= 2)

    const bf16x8 qB0 = load8(Qp + (size_t)(q0 + m) * D_K + quad * 8);
    const bf16x8 qB1 = load8(Qp + (size_t)(q0 + m) * D_K + 32 + quad * 8);

    f32x4 oacc[4];
#pragma unroll
    for (int c = 0; c < 4; c++) oacc[c] = (f32x4){0.f, 0.f, 0.f, 0.f};
    f32x4 accL = (f32x4){0.f, 0.f, 0.f, 0.f};      // l for q = q0+quad*4+r

    stage(0, 0);
    stage(64, 1);
#pragma unroll 1
    for (int p = 0; p < T; p += 2) {
        __syncthreads();             // tiles p, p+1 staged (issued pair p-2)
        if (p + 2 < T) stage((p + 2) * 64, (p + 2) & 3);
        if (p + 3 < T) stage((p + 3) * 64, (p + 3) & 3);

        const int k0A = p * 64, k0B = k0A + 64;
        const __bf16* KcA = &Ks[p & 3][0];
        const __bf16* KcB = &Ks[(p + 1) & 3][0];
        const __bf16* VcA = &Vt[p & 3][0];
        const __bf16* VcB = &Vt[(p + 1) & 3][0];
        const bool mkA = (p     >= myDiag);        // partial or all-zero mask
        const bool mkB = (p + 1 >= myDiag);

        // ---- QK^T for BOTH tiles, interleaved per kb; exp2; pack ----
        uint32_t w0A[4], w1A[4], w0B[4], w1B[4];
#pragma unroll
        for (int kb = 0; kb < 4; kb++) {
            const int rK = kb * 16 + m;
            const int o1 = (quad ^ (rK & 7)) * 8;
            const int o2 = ((quad + 4) ^ (rK & 7)) * 8;
            f32x4 sA = (f32x4){0.f, 0.f, 0.f, 0.f};
            sA = MFMA16(load8(KcA + rK * 64 + o1), qB0, sA);
            sA = MFMA16(load8(KcA + rK * 64 + o2), qB1, sA);
            f32x4 sB = (f32x4){0.f, 0.f, 0.f, 0.f};
            sB = MFMA16(load8(KcB + rK * 64 + o1), qB0, sB);
            sB = MFMA16(load8(KcB + rK * 64 + o2), qB1, sB);
            const int q    = q0 + m;
            const int keyA = k0A + kb * 16 + quad * 4;
            const int keyB = k0B + kb * 16 + quad * 4;
            float eA[4], eB[4];
#pragma unroll
            for (int r = 0; r < 4; r++) {
                float ea = __builtin_amdgcn_exp2f(sA[r]);
                if (mkA) ea = (keyA + r <= q) ? ea : 0.f;
                eA[r] = ea;
                float eb = __builtin_amdgcn_exp2f(sB[r]);
                if (mkB) eb = (keyB + r <= q) ? eb : 0.f;
                eB[r] = eb;
            }
            w0A[kb] = cvtpk(eA[0], eA[1]); w1A[kb] = cvtpk(eA[2], eA[3]);
            w0B[kb] = cvtpk(eB[0], eB[1]); w1B[kb] = cvtpk(eB[2], eB[3]);
        }

        // ---- zip-permlane redistribution, both tiles ----
        uint32_t a0 = w0A[0], a2 = w0A[1]; swap32(a0, a2); swap16(a0, a2);
        uint32_t a1 = w1A[0], a3 = w1A[1]; swap32(a1, a3); swap16(a1, a3);
        uint32_t a4 = w0A[2], a6 = w0A[3]; swap32(a4, a6); swap16(a4, a6);
        uint32_t a5 = w1A[2], a7 = w1A[3]; swap32(a5, a7); swap16(a5, a7);
        const bf16x8 pfAA = __builtin_bit_cast(bf16x8, (u32x4){a0, a1, a2, a3});
        const bf16x8 pfBA = __builtin_bit_cast(bf16x8, (u32x4){a4, a5, a6, a7});
        uint32_t c0 = w0B[0], c2 = w0B[1]; swap32(c0, c2); swap16(c0, c2);
        uint32_t c1 = w1B[0], c3 = w1B[1]; swap32(c1, c3); swap16(c1, c3);
        uint32_t c4 = w0B[2], c6 = w0B[3]; swap32(c4, c6); swap16(c4, c6);
        uint32_t c5 = w1B[2], c7 = w1B[3]; swap32(c5, c7); swap16(c5, c7);
        const bf16x8 pfAB = __builtin_bit_cast(bf16x8, (u32x4){c0, c1, c2, c3});
        const bf16x8 pfBB = __builtin_bit_cast(bf16x8, (u32x4){c4, c5, c6, c7});

        // ---- row-sums (ones-MFMA), both tiles ----
        accL = MFMA16(pfAA, vone, accL);
        accL = MFMA16(pfBA, vone, accL);
        accL = MFMA16(pfAB, vone, accL);
        accL = MFMA16(pfBB, vone, accL);

        // ---- P.V, both tiles interleaved per output column ----
#pragma unroll
        for (int c = 0; c < 4; c++) {
            const int rV = c * 16 + m;
            const int o1 = (quad ^ (rV & 7)) * 8;
            const int o2 = ((quad + 4) ^ (rV & 7)) * 8;
            oacc[c] = MFMA16(pfAA, load8(VcA + rV * 64 + o1), oacc[c]);
            oacc[c] = MFMA16(pfBA, load8(VcA + rV * 64 + o2), oacc[c]);
            oacc[c] = MFMA16(pfAB, load8(VcB + rV * 64 + o1), oacc[c]);
            oacc[c] = MFMA16(pfBB, load8(VcB + rV * 64 + o2), oacc[c]);
        }
    }

    // ---- epilogue: l is already per-register in accL ----
#pragma unroll
    for (int r = 0; r < 4; r++) {
        const float inv = 1.f / accL[r];
        const int srow = q0 + quad * 4 + r;
#pragma unroll
        for (int c = 0; c < 4; c++) {
            const size_t o2 = ((size_t)(b * SEQ + srow)) * D_MODEL + h * D_K + c * 16 + m;
            Cc[o2] = (__bf16)(oacc[c][r] * inv);
        }
    }
}

// ---------------------------------------------------------------------------
// Output projection (R16 config): Out = Cc * Wo^T + bo (fp32). 64x64 tile,
// grid (64,16) = 1024 blocks = 4/CU, double-buffered prefetch loop (one
// barrier per K-step), both operands via gload16 (bf16).
// ---------------------------------------------------------------------------
__global__ __launch_bounds__(256) void oproj_kernel(
    const __bf16* __restrict__ Cc,
    const __bf16* __restrict__ Wob,
    const float* __restrict__ bo,
    float* __restrict__ Out)
{
    __shared__ alignas(16) __bf16 As[2][64 * 64];  // ping-pong, 8 KB each
    __shared__ alignas(16) __bf16 Bs[2][64 * 64];  // ping-pong, 8 KB each

    const int lane = threadIdx.x & 63;
    const int wid  = threadIdx.x >> 6;
    const int m    = lane & 15;
    const int quad = lane >> 4;
    const int wrow = wid >> 1, wcol = wid & 1;
    const int row0 = blockIdx.x * 64;
    const int col0 = blockIdx.y * 64;

    auto stage = [&](int k0, int buf) {
#pragma unroll
        for (int i = 0; i < 2; i++) {
            const int slot = wid * 128 + i * 64 + lane;
            const int row  = slot >> 3;
            const int cg   = (slot & 7) ^ (row & 7);
            gload16(Cc + (size_t)(row0 + row) * D_MODEL + k0 + cg * 8,
                    (const char*)&As[buf][0] + (size_t)slot * 16);
            gload16(Wob + (size_t)(col0 + row) * D_MODEL + k0 + cg * 8,
                    (const char*)&Bs[buf][0] + (size_t)slot * 16);
        }
    };

    f32x4 acc[2][2];
#pragma unroll
    for (int i = 0; i < 2; i++)
#pragma unroll
        for (int j = 0; j < 2; j++) acc[i][j] = (f32x4){0.f, 0.f, 0.f, 0.f};

    stage(0, 0);
    int cur = 0;
#pragma unroll 1
    for (int k0 = 0; k0 < D_MODEL; k0 += 64) {
        __syncthreads();                       // buffer `cur` staged
        if (k0 + 64 < D_MODEL) stage(k0 + 64, cur ^ 1);

        bf16x8 a2[2][2], b2[2][2];
#pragma unroll
        for (int ks = 0; ks < 2; ks++) {
#pragma unroll
            for (int i = 0; i < 2; i++) {
                const int rA = wrow * 32 + i * 16 + m;
                a2[ks][i] = load8(&As[cur][0] + rA * 64 + (((ks * 4 + quad) ^ (rA & 7)) * 8));
                const int rB = wcol * 32 + i * 16 + m;
                b2[ks][i] = load8(&Bs[cur][0] + rB * 64 + (((ks * 4 + quad) ^ (rB & 7)) * 8));
            }
        }
#pragma unroll
        for (int ks = 0; ks < 2; ks++)
#pragma unroll
            for (int i = 0; i < 2; i++)
#pragma unroll
                for (int j = 0; j < 2; j++)
                    acc[i][j] = MFMA16(a2[ks][i], b2[ks][j], acc[i][j]);
        cur ^= 1;
    }

#pragma unroll
    for (int i = 0; i < 2; i++) {
#pragma unroll
        for (int r = 0; r < 4; r++) {
            const int R = row0 + wrow * 32 + i * 16 + quad * 4 + r;
#pragma unroll
            for (int j = 0; j < 2; j++) {
                const int E = col0 + wcol * 32 + j * 16 + m;
                Out[(size_t)R * D_MODEL + E] = acc[i][j][r] + bo[E];
            }
        }
    }
}

// ---------------------------------------------------------------------------
extern "C" void kernel_launch(void* const* d_in, const int* in_sizes, int n_in,
                              void* d_out, int out_size, void* d_ws, size_t ws_size,
                              hipStream_t stream) {
    const float* x  = (const float*)d_in[0];
    const float* Wq = (const float*)d_in[1];
    const float* Wk = (const float*)d_in[2];
    const float* Wv = (const float*)d_in[3];
    const float* Wo = (const float*)d_in[4];
    const float* bo = (const float*)d_in[5];
    // d_in[6] = causal mask — recomputed from indices, not read.

    const size_t elems  = (size_t)M_TOTAL * D_MODEL;   // 4194304
    const size_t welems = (size_t)D_MODEL * D_MODEL;   // 1048576
    __bf16* xb  = (__bf16*)d_ws;       // seg0: x (bf16) -> later Cc (aliased)
    __bf16* Qb  = xb + elems;
    __bf16* Kb  = Qb + elems;
    __bf16* Vtg = Kb + elems;          // [32][64][2048]  (V^T)
    __bf16* Wqb = Vtg + elems;
    __bf16* Wkb = Wqb + welems;
    __bf16* Wvb = Wkb + welems;
    __bf16* Wob = Wvb + welems;        // end: 40 MB
    __bf16* Cc  = xb;

    // 0) all fp32 -> bf16 conversions in one launch
    convert_all<<<dim3(4096), 256, 0, stream>>>(
        x, Wq, Wk, Wv, Wo, xb, Wqb, Wkb, Wvb, Wob);

    // 1) QKV projections (Q pre-scaled by 0.125*log2e), dbuf prefetch loop
    qkv_kernel<<<dim3(M_TOTAL / 128, 3 * D_MODEL / 128), 256, 0, stream>>>(
        xb, Wqb, Wkb, Wvb, Qb, Kb, Vtg);

    // 2) causal flash attention: 8-wave blocks, pair-tile ILP, 4-buffer LDS
    attn_kernel<<<dim3(BATCH * NUM_HEADS, 16), 512, 0, stream>>>(
        Qb, Kb, Vtg, Cc);

    // 3) output projection + bias -> fp32 out (64x64 tiles, dbuf prefetch)
    oproj_kernel<<<dim3(M_TOTAL / 64, D_MODEL / 64), 256, 0, stream>>>(
        Cc, Wob, bo, (float*)d_out);
}